// Round 2
// baseline (454.549 us; speedup 1.0000x reference)
//
#include <hip/hip_runtime.h>

// VQ codebook: z_e (262144, 64) f32, embeddings (512, 64) f32.
// Outputs (flat f32 in d_out): z_q_st [N*D], indices-as-float [N], loss [1].
//
// R2: token row in 16 NAMED float4 registers (no indexable array -> no scratch
// spill, cf. R1's VGPR=64 + 64MB excess WRITE_SIZE). Macro-expanded d-loop,
// 2 codes/iter, 4 independent FMA chains. emb reads are wave-uniform -> s_load.

static constexpr int N_TOK = 262144;
static constexpr int K     = 512;
static constexpr int D     = 64;
static constexpr int BLK   = 256;
static constexpr int NBLK  = N_TOK / BLK;  // 1024

// ---- kernel 0: esq[k] = ||e_k||^2 ------------------------------------------
__global__ void esq_kernel(const float* __restrict__ emb, float* __restrict__ esq) {
  int k = threadIdx.x;
  if (k < K) {
    const float4* row = reinterpret_cast<const float4*>(emb + (size_t)k * D);
    float s = 0.f;
#pragma unroll
    for (int i = 0; i < D / 4; ++i) {
      float4 v = row[i];
      s = fmaf(v.x, v.x, s);
      s = fmaf(v.y, v.y, s);
      s = fmaf(v.z, v.z, s);
      s = fmaf(v.w, v.w, s);
    }
    esq[k] = s;
  }
}

#define DOT4(ACC, Z, EV)              \
  ACC = fmaf((Z).x, (EV).x, ACC);     \
  ACC = fmaf((Z).y, (EV).y, ACC);     \
  ACC = fmaf((Z).z, (EV).z, ACC);     \
  ACC = fmaf((Z).w, (EV).w, ACC);

// ---- kernel 1: per-token argmin + gather + partial loss --------------------
__global__ __launch_bounds__(BLK) void vq_main(
    const float* __restrict__ z_e, const float* __restrict__ emb,
    const float* __restrict__ esq, float* __restrict__ out_zq,
    float* __restrict__ out_idx, float* __restrict__ block_loss) {
  const int n = blockIdx.x * BLK + threadIdx.x;

  // Token row: 16 named float4 registers (statically addressed everywhere).
  const float4* zr = reinterpret_cast<const float4*>(z_e + (size_t)n * D);
  float4 z0  = zr[0],  z1  = zr[1],  z2  = zr[2],  z3  = zr[3];
  float4 z4  = zr[4],  z5  = zr[5],  z6  = zr[6],  z7  = zr[7];
  float4 z8  = zr[8],  z9  = zr[9],  z10 = zr[10], z11 = zr[11];
  float4 z12 = zr[12], z13 = zr[13], z14 = zr[14], z15 = zr[15];

  float best = 3.402823466e38f;
  int   bidx = 0;

  const float4* E = reinterpret_cast<const float4*>(emb);  // 16 float4 per code

  for (int k = 0; k < K; k += 2) {
    const float4* e0 = E + (size_t)k * (D / 4);
    const float4* e1 = e0 + (D / 4);
    // 4 independent chains: a0/a1 (code k, even/odd quads), b0/b1 (code k+1).
    float a0 = 0.f, a1 = 0.f, b0 = 0.f, b1 = 0.f;
    {
      float4 ea, eb;
      ea = e0[0];  DOT4(a0, z0, ea);   eb = e1[0];  DOT4(b0, z0, eb);
      ea = e0[1];  DOT4(a1, z1, ea);   eb = e1[1];  DOT4(b1, z1, eb);
      ea = e0[2];  DOT4(a0, z2, ea);   eb = e1[2];  DOT4(b0, z2, eb);
      ea = e0[3];  DOT4(a1, z3, ea);   eb = e1[3];  DOT4(b1, z3, eb);
      ea = e0[4];  DOT4(a0, z4, ea);   eb = e1[4];  DOT4(b0, z4, eb);
      ea = e0[5];  DOT4(a1, z5, ea);   eb = e1[5];  DOT4(b1, z5, eb);
      ea = e0[6];  DOT4(a0, z6, ea);   eb = e1[6];  DOT4(b0, z6, eb);
      ea = e0[7];  DOT4(a1, z7, ea);   eb = e1[7];  DOT4(b1, z7, eb);
      ea = e0[8];  DOT4(a0, z8, ea);   eb = e1[8];  DOT4(b0, z8, eb);
      ea = e0[9];  DOT4(a1, z9, ea);   eb = e1[9];  DOT4(b1, z9, eb);
      ea = e0[10]; DOT4(a0, z10, ea);  eb = e1[10]; DOT4(b0, z10, eb);
      ea = e0[11]; DOT4(a1, z11, ea);  eb = e1[11]; DOT4(b1, z11, eb);
      ea = e0[12]; DOT4(a0, z12, ea);  eb = e1[12]; DOT4(b0, z12, eb);
      ea = e0[13]; DOT4(a1, z13, ea);  eb = e1[13]; DOT4(b1, z13, eb);
      ea = e0[14]; DOT4(a0, z14, ea);  eb = e1[14]; DOT4(b0, z14, eb);
      ea = e0[15]; DOT4(a1, z15, ea);  eb = e1[15]; DOT4(b1, z15, eb);
    }
    float sa = fmaf(-2.f, a0 + a1, esq[k + 0]);
    float sb = fmaf(-2.f, b0 + b1, esq[k + 1]);
    // Ascending-k strict < keeps jnp.argmin first-min tie semantics.
    if (sa < best) { best = sa; bidx = k + 0; }
    if (sb < best) { best = sb; bidx = k + 1; }
  }

  // Gather chosen code, write z_q_st (= q exactly), accumulate (q - z)^2.
  float lsum = 0.f;
  {
    const float4* er = reinterpret_cast<const float4*>(emb + (size_t)bidx * D);
    float4* orow = reinterpret_cast<float4*>(out_zq + (size_t)n * D);
#define TAIL(i, ZI)                                        \
    {                                                      \
      float4 q = er[i];                                    \
      float dx = q.x - ZI.x, dy = q.y - ZI.y;              \
      float dz = q.z - ZI.z, dw = q.w - ZI.w;              \
      float4 st;                                           \
      st.x = ZI.x + dx; st.y = ZI.y + dy;                  \
      st.z = ZI.z + dz; st.w = ZI.w + dw;                  \
      orow[i] = st;                                        \
      lsum = fmaf(dx, dx, lsum);                           \
      lsum = fmaf(dy, dy, lsum);                           \
      lsum = fmaf(dz, dz, lsum);                           \
      lsum = fmaf(dw, dw, lsum);                           \
    }
    TAIL(0, z0)   TAIL(1, z1)   TAIL(2, z2)   TAIL(3, z3)
    TAIL(4, z4)   TAIL(5, z5)   TAIL(6, z6)   TAIL(7, z7)
    TAIL(8, z8)   TAIL(9, z9)   TAIL(10, z10) TAIL(11, z11)
    TAIL(12, z12) TAIL(13, z13) TAIL(14, z14) TAIL(15, z15)
#undef TAIL
  }

  out_idx[n] = (float)bidx;

  // Deterministic per-block loss reduction.
  __shared__ float red[BLK];
  red[threadIdx.x] = lsum;
  __syncthreads();
#pragma unroll
  for (int off = BLK / 2; off > 0; off >>= 1) {
    if (threadIdx.x < off) red[threadIdx.x] += red[threadIdx.x + off];
    __syncthreads();
  }
  if (threadIdx.x == 0) block_loss[blockIdx.x] = red[0];
}

// ---- kernel 2: finalize loss (deterministic tree) --------------------------
__global__ __launch_bounds__(BLK) void loss_finalize(
    const float* __restrict__ bl, float* __restrict__ out_loss) {
  __shared__ float sm[BLK];
  float s = 0.f;
  for (int i = threadIdx.x; i < NBLK; i += BLK) s += bl[i];
  sm[threadIdx.x] = s;
  __syncthreads();
#pragma unroll
  for (int off = BLK / 2; off > 0; off >>= 1) {
    if (threadIdx.x < off) sm[threadIdx.x] += sm[threadIdx.x + off];
    __syncthreads();
  }
  if (threadIdx.x == 0) out_loss[0] = sm[0] * (1.0f / 16777216.0f);  // / (N*D)
}

extern "C" void kernel_launch(void* const* d_in, const int* in_sizes, int n_in,
                              void* d_out, int out_size, void* d_ws, size_t ws_size,
                              hipStream_t stream) {
  const float* z_e = (const float*)d_in[0];
  const float* emb = (const float*)d_in[1];

  float* out      = (float*)d_out;
  float* out_zq   = out;                          // N*D
  float* out_idx  = out + (size_t)N_TOK * D;      // N
  float* out_loss = out_idx + N_TOK;              // 1

  float* esq = (float*)d_ws;       // K floats
  float* bl  = esq + K;            // NBLK floats

  esq_kernel<<<1, K, 0, stream>>>(emb, esq);
  vq_main<<<NBLK, BLK, 0, stream>>>(z_e, emb, esq, out_zq, out_idx, bl);
  loss_finalize<<<1, BLK, 0, stream>>>(bl, out_loss);
}

// Round 3
// 437.960 us; speedup vs baseline: 1.0379x; 1.0379x over previous
//
#include <hip/hip_runtime.h>

// VQ codebook: z_e (262144, 64) f32, embeddings (512, 64) f32.
// Outputs (flat f32 in d_out): z_q_st [N*D], indices-as-float [N], loss [1].
//
// R3: codebook resident in LDS (128 KiB, broadcast ds_read_b128 -> conflict-
// free, LDS pipe overlaps VALU). BLK=1024, grid=256 -> exactly 1 block/CU,
// 16 waves/CU. __launch_bounds__(1024,4) caps VGPR at 128 (z=64 + window).
// R1/R2 lesson: VMEM-sourced inner loop spilled z to scratch (WRITE_SIZE
// +59MB canary) and stalled on vmcnt (VALUBusy 27%).

static constexpr int N_TOK = 262144;
static constexpr int K     = 512;
static constexpr int D     = 64;
static constexpr int BLK   = 1024;
static constexpr int NBLK  = N_TOK / BLK;  // 256

// ---- kernel 0: esq[k] = ||e_k||^2 ------------------------------------------
__global__ void esq_kernel(const float* __restrict__ emb, float* __restrict__ esq) {
  int k = threadIdx.x;
  if (k < K) {
    const float4* row = reinterpret_cast<const float4*>(emb + (size_t)k * D);
    float s = 0.f;
#pragma unroll
    for (int i = 0; i < D / 4; ++i) {
      float4 v = row[i];
      s = fmaf(v.x, v.x, s);
      s = fmaf(v.y, v.y, s);
      s = fmaf(v.z, v.z, s);
      s = fmaf(v.w, v.w, s);
    }
    esq[k] = s;
  }
}

#define DOT4(ACC, Z, EV)              \
  ACC = fmaf((Z).x, (EV).x, ACC);     \
  ACC = fmaf((Z).y, (EV).y, ACC);     \
  ACC = fmaf((Z).z, (EV).z, ACC);     \
  ACC = fmaf((Z).w, (EV).w, ACC);

// ---- kernel 1: per-token argmin + gather + partial loss --------------------
__global__ __launch_bounds__(BLK, 4) void vq_main(
    const float* __restrict__ z_e, const float* __restrict__ emb,
    const float* __restrict__ esq, float* __restrict__ out_zq,
    float* __restrict__ out_idx, float* __restrict__ block_loss) {
  __shared__ float4 lds_emb[K * (D / 4)];  // 8192 x 16B = 128 KiB
  __shared__ float  lds_esq[K];            // 2 KiB
  __shared__ float  red[BLK];              // 4 KiB

  const int t = threadIdx.x;
  const int n = blockIdx.x * BLK + t;

  // Stage codebook + esq into LDS (coalesced, one-time; emb is L2/L3-hot).
  {
    const float4* E = reinterpret_cast<const float4*>(emb);
#pragma unroll
    for (int i = 0; i < (K * D / 4) / BLK; ++i)  // 8 iters
      lds_emb[t + i * BLK] = E[t + i * BLK];
    if (t < K) lds_esq[t] = esq[t];
  }

  // Token row: 16 named float4 registers.
  const float4* zr = reinterpret_cast<const float4*>(z_e + (size_t)n * D);
  float4 z0  = zr[0],  z1  = zr[1],  z2  = zr[2],  z3  = zr[3];
  float4 z4  = zr[4],  z5  = zr[5],  z6  = zr[6],  z7  = zr[7];
  float4 z8  = zr[8],  z9  = zr[9],  z10 = zr[10], z11 = zr[11];
  float4 z12 = zr[12], z13 = zr[13], z14 = zr[14], z15 = zr[15];

  __syncthreads();

  float best = 3.402823466e38f;
  int   bidx = 0;

  for (int k = 0; k < K; k += 2) {
    const float4* e0 = lds_emb + (size_t)k * (D / 4);  // broadcast reads
    const float4* e1 = e0 + (D / 4);
    float a0 = 0.f, a1 = 0.f, b0 = 0.f, b1 = 0.f;
    {
      float4 ea, eb;
      ea = e0[0];  DOT4(a0, z0, ea);   eb = e1[0];  DOT4(b0, z0, eb);
      ea = e0[1];  DOT4(a1, z1, ea);   eb = e1[1];  DOT4(b1, z1, eb);
      ea = e0[2];  DOT4(a0, z2, ea);   eb = e1[2];  DOT4(b0, z2, eb);
      ea = e0[3];  DOT4(a1, z3, ea);   eb = e1[3];  DOT4(b1, z3, eb);
      ea = e0[4];  DOT4(a0, z4, ea);   eb = e1[4];  DOT4(b0, z4, eb);
      ea = e0[5];  DOT4(a1, z5, ea);   eb = e1[5];  DOT4(b1, z5, eb);
      ea = e0[6];  DOT4(a0, z6, ea);   eb = e1[6];  DOT4(b0, z6, eb);
      ea = e0[7];  DOT4(a1, z7, ea);   eb = e1[7];  DOT4(b1, z7, eb);
      ea = e0[8];  DOT4(a0, z8, ea);   eb = e1[8];  DOT4(b0, z8, eb);
      ea = e0[9];  DOT4(a1, z9, ea);   eb = e1[9];  DOT4(b1, z9, eb);
      ea = e0[10]; DOT4(a0, z10, ea);  eb = e1[10]; DOT4(b0, z10, eb);
      ea = e0[11]; DOT4(a1, z11, ea);  eb = e1[11]; DOT4(b1, z11, eb);
      ea = e0[12]; DOT4(a0, z12, ea);  eb = e1[12]; DOT4(b0, z12, eb);
      ea = e0[13]; DOT4(a1, z13, ea);  eb = e1[13]; DOT4(b1, z13, eb);
      ea = e0[14]; DOT4(a0, z14, ea);  eb = e1[14]; DOT4(b0, z14, eb);
      ea = e0[15]; DOT4(a1, z15, ea);  eb = e1[15]; DOT4(b1, z15, eb);
    }
    float sa = fmaf(-2.f, a0 + a1, lds_esq[k + 0]);
    float sb = fmaf(-2.f, b0 + b1, lds_esq[k + 1]);
    // Ascending-k strict < keeps jnp.argmin first-min tie semantics.
    if (sa < best) { best = sa; bidx = k + 0; }
    if (sb < best) { best = sb; bidx = k + 1; }
  }

  // Gather chosen code from GLOBAL emb (L2-hot; LDS gather would be
  // all-lanes-same-bank). Write z_q_st (= q exactly), accumulate (q-z)^2.
  float lsum = 0.f;
  {
    const float4* er = reinterpret_cast<const float4*>(emb + (size_t)bidx * D);
    float4* orow = reinterpret_cast<float4*>(out_zq + (size_t)n * D);
#define TAIL(i, ZI)                                        \
    {                                                      \
      float4 q = er[i];                                    \
      float dx = q.x - ZI.x, dy = q.y - ZI.y;              \
      float dz = q.z - ZI.z, dw = q.w - ZI.w;              \
      float4 st;                                           \
      st.x = ZI.x + dx; st.y = ZI.y + dy;                  \
      st.z = ZI.z + dz; st.w = ZI.w + dw;                  \
      orow[i] = st;                                        \
      lsum = fmaf(dx, dx, lsum);                           \
      lsum = fmaf(dy, dy, lsum);                           \
      lsum = fmaf(dz, dz, lsum);                           \
      lsum = fmaf(dw, dw, lsum);                           \
    }
    TAIL(0, z0)   TAIL(1, z1)   TAIL(2, z2)   TAIL(3, z3)
    TAIL(4, z4)   TAIL(5, z5)   TAIL(6, z6)   TAIL(7, z7)
    TAIL(8, z8)   TAIL(9, z9)   TAIL(10, z10) TAIL(11, z11)
    TAIL(12, z12) TAIL(13, z13) TAIL(14, z14) TAIL(15, z15)
#undef TAIL
  }

  out_idx[n] = (float)bidx;

  // Deterministic per-block loss reduction.
  red[t] = lsum;
  __syncthreads();
#pragma unroll
  for (int off = BLK / 2; off > 0; off >>= 1) {
    if (t < off) red[t] += red[t + off];
    __syncthreads();
  }
  if (t == 0) block_loss[blockIdx.x] = red[0];
}

// ---- kernel 2: finalize loss (deterministic tree) --------------------------
__global__ __launch_bounds__(256) void loss_finalize(
    const float* __restrict__ bl, float* __restrict__ out_loss) {
  __shared__ float sm[256];
  float s = 0.f;
  for (int i = threadIdx.x; i < NBLK; i += 256) s += bl[i];
  sm[threadIdx.x] = s;
  __syncthreads();
#pragma unroll
  for (int off = 128; off > 0; off >>= 1) {
    if (threadIdx.x < off) sm[threadIdx.x] += sm[threadIdx.x + off];
    __syncthreads();
  }
  if (threadIdx.x == 0) out_loss[0] = sm[0] * (1.0f / 16777216.0f);  // / (N*D)
}

extern "C" void kernel_launch(void* const* d_in, const int* in_sizes, int n_in,
                              void* d_out, int out_size, void* d_ws, size_t ws_size,
                              hipStream_t stream) {
  const float* z_e = (const float*)d_in[0];
  const float* emb = (const float*)d_in[1];

  float* out      = (float*)d_out;
  float* out_zq   = out;                          // N*D
  float* out_idx  = out + (size_t)N_TOK * D;      // N
  float* out_loss = out_idx + N_TOK;              // 1

  float* esq = (float*)d_ws;       // K floats
  float* bl  = esq + K;            // NBLK floats

  esq_kernel<<<1, K, 0, stream>>>(emb, esq);
  vq_main<<<NBLK, BLK, 0, stream>>>(z_e, emb, esq, out_zq, out_idx, bl);
  loss_finalize<<<1, 256, 0, stream>>>(bl, out_loss);
}

// Round 4
// 407.215 us; speedup vs baseline: 1.1162x; 1.0755x over previous
//
#include <hip/hip_runtime.h>

// VQ codebook: z_e (262144, 64) f32, embeddings (512, 64) f32.
// Outputs (flat f32 in d_out): z_q_st [N*D], indices-as-float [N], loss [1].
//
// R4: (a) amdgpu_waves_per_eu(4,4) pins the register budget at 128 VGPR --
// R1/R2/R3 all spilled z because the allocator targeted 8 waves/EU (64 VGPR)
// regardless of __launch_bounds__ (VGPR_Count=64 + WRITE_SIZE spill canary).
// (b) codebook read via wave-uniform global loads -> s_load into SGPRs;
// v_fma takes the SGPR operand directly. No LDS (broadcast ds_read_b128
// writeback is ~8cyc/instr on the shared per-CU LDS pipe = as expensive as
// the FMAs it feeds). VALU floor: 512 codes * 64 FMA * 2cyc * 4waves/SIMD
// = 262k cyc = ~109 us.

static constexpr int N_TOK = 262144;
static constexpr int K     = 512;
static constexpr int D     = 64;
static constexpr int BLK   = 256;
static constexpr int NBLK  = N_TOK / BLK;  // 1024

// ---- kernel 0: esq[k] = ||e_k||^2 ------------------------------------------
__global__ void esq_kernel(const float* __restrict__ emb, float* __restrict__ esq) {
  int k = threadIdx.x;
  if (k < K) {
    const float4* row = reinterpret_cast<const float4*>(emb + (size_t)k * D);
    float s = 0.f;
#pragma unroll
    for (int i = 0; i < D / 4; ++i) {
      float4 v = row[i];
      s = fmaf(v.x, v.x, s);
      s = fmaf(v.y, v.y, s);
      s = fmaf(v.z, v.z, s);
      s = fmaf(v.w, v.w, s);
    }
    esq[k] = s;
  }
}

// 4 dims of a dot product: z quad (VGPRs) * e[base..base+3] (scalar/SGPR).
#define DOT4S(ACC, ZQ, EP, BASE)                  \
  ACC = fmaf((ZQ).x, (EP)[(BASE) + 0], ACC);      \
  ACC = fmaf((ZQ).y, (EP)[(BASE) + 1], ACC);      \
  ACC = fmaf((ZQ).z, (EP)[(BASE) + 2], ACC);      \
  ACC = fmaf((ZQ).w, (EP)[(BASE) + 3], ACC);

// ---- kernel 1: per-token argmin + gather + partial loss --------------------
__global__ __launch_bounds__(BLK)
__attribute__((amdgpu_waves_per_eu(4, 4)))
void vq_main(
    const float* __restrict__ z_e, const float* __restrict__ emb,
    const float* __restrict__ esq, float* __restrict__ out_zq,
    float* __restrict__ out_idx, float* __restrict__ block_loss) {
  const int t = threadIdx.x;
  const int n = blockIdx.x * BLK + t;

  // Token row: 16 named float4 registers (statically addressed everywhere).
  const float4* zr = reinterpret_cast<const float4*>(z_e + (size_t)n * D);
  float4 z0  = zr[0],  z1  = zr[1],  z2  = zr[2],  z3  = zr[3];
  float4 z4  = zr[4],  z5  = zr[5],  z6  = zr[6],  z7  = zr[7];
  float4 z8  = zr[8],  z9  = zr[9],  z10 = zr[10], z11 = zr[11];
  float4 z12 = zr[12], z13 = zr[13], z14 = zr[14], z15 = zr[15];

  float best = 3.402823466e38f;
  int   bidx = 0;

  for (int k = 0; k < K; k += 2) {
    // Wave-uniform pointers -> scalar loads (s_load) into SGPRs.
    const float* e0 = emb + (size_t)k * D;
    const float* e1 = e0 + D;
    // 4 independent FMA chains: a0/a1 (code k), b0/b1 (code k+1).
    float a0 = 0.f, a1 = 0.f, b0 = 0.f, b1 = 0.f;
    DOT4S(a0, z0,  e0, 0)   DOT4S(b0, z0,  e1, 0)
    DOT4S(a1, z1,  e0, 4)   DOT4S(b1, z1,  e1, 4)
    DOT4S(a0, z2,  e0, 8)   DOT4S(b0, z2,  e1, 8)
    DOT4S(a1, z3,  e0, 12)  DOT4S(b1, z3,  e1, 12)
    DOT4S(a0, z4,  e0, 16)  DOT4S(b0, z4,  e1, 16)
    DOT4S(a1, z5,  e0, 20)  DOT4S(b1, z5,  e1, 20)
    DOT4S(a0, z6,  e0, 24)  DOT4S(b0, z6,  e1, 24)
    DOT4S(a1, z7,  e0, 28)  DOT4S(b1, z7,  e1, 28)
    DOT4S(a0, z8,  e0, 32)  DOT4S(b0, z8,  e1, 32)
    DOT4S(a1, z9,  e0, 36)  DOT4S(b1, z9,  e1, 36)
    DOT4S(a0, z10, e0, 40)  DOT4S(b0, z10, e1, 40)
    DOT4S(a1, z11, e0, 44)  DOT4S(b1, z11, e1, 44)
    DOT4S(a0, z12, e0, 48)  DOT4S(b0, z12, e1, 48)
    DOT4S(a1, z13, e0, 52)  DOT4S(b1, z13, e1, 52)
    DOT4S(a0, z14, e0, 56)  DOT4S(b0, z14, e1, 56)
    DOT4S(a1, z15, e0, 60)  DOT4S(b1, z15, e1, 60)
    float sa = fmaf(-2.f, a0 + a1, esq[k + 0]);
    float sb = fmaf(-2.f, b0 + b1, esq[k + 1]);
    // Ascending-k strict < keeps jnp.argmin first-min tie semantics.
    if (sa < best) { best = sa; bidx = k + 0; }
    if (sb < best) { best = sb; bidx = k + 1; }
  }

  // Gather chosen code (per-lane divergent, L2-hot). Write z_q_st (= q
  // exactly), accumulate (q - z)^2.
  float lsum = 0.f;
  {
    const float4* er = reinterpret_cast<const float4*>(emb + (size_t)bidx * D);
    float4* orow = reinterpret_cast<float4*>(out_zq + (size_t)n * D);
#define TAIL(i, ZI)                                        \
    {                                                      \
      float4 q = er[i];                                    \
      float dx = q.x - ZI.x, dy = q.y - ZI.y;              \
      float dz = q.z - ZI.z, dw = q.w - ZI.w;              \
      float4 st;                                           \
      st.x = ZI.x + dx; st.y = ZI.y + dy;                  \
      st.z = ZI.z + dz; st.w = ZI.w + dw;                  \
      orow[i] = st;                                        \
      lsum = fmaf(dx, dx, lsum);                           \
      lsum = fmaf(dy, dy, lsum);                           \
      lsum = fmaf(dz, dz, lsum);                           \
      lsum = fmaf(dw, dw, lsum);                           \
    }
    TAIL(0, z0)   TAIL(1, z1)   TAIL(2, z2)   TAIL(3, z3)
    TAIL(4, z4)   TAIL(5, z5)   TAIL(6, z6)   TAIL(7, z7)
    TAIL(8, z8)   TAIL(9, z9)   TAIL(10, z10) TAIL(11, z11)
    TAIL(12, z12) TAIL(13, z13) TAIL(14, z14) TAIL(15, z15)
#undef TAIL
  }

  out_idx[n] = (float)bidx;

  // Deterministic per-block loss reduction.
  __shared__ float red[BLK];
  red[t] = lsum;
  __syncthreads();
#pragma unroll
  for (int off = BLK / 2; off > 0; off >>= 1) {
    if (t < off) red[t] += red[t + off];
    __syncthreads();
  }
  if (t == 0) block_loss[blockIdx.x] = red[0];
}

// ---- kernel 2: finalize loss (deterministic tree) --------------------------
__global__ __launch_bounds__(256) void loss_finalize(
    const float* __restrict__ bl, float* __restrict__ out_loss) {
  __shared__ float sm[256];
  float s = 0.f;
  for (int i = threadIdx.x; i < NBLK; i += 256) s += bl[i];
  sm[threadIdx.x] = s;
  __syncthreads();
#pragma unroll
  for (int off = 128; off > 0; off >>= 1) {
    if (threadIdx.x < off) sm[threadIdx.x] += sm[threadIdx.x + off];
    __syncthreads();
  }
  if (threadIdx.x == 0) out_loss[0] = sm[0] * (1.0f / 16777216.0f);  // / (N*D)
}

extern "C" void kernel_launch(void* const* d_in, const int* in_sizes, int n_in,
                              void* d_out, int out_size, void* d_ws, size_t ws_size,
                              hipStream_t stream) {
  const float* z_e = (const float*)d_in[0];
  const float* emb = (const float*)d_in[1];

  float* out      = (float*)d_out;
  float* out_zq   = out;                          // N*D
  float* out_idx  = out + (size_t)N_TOK * D;      // N
  float* out_loss = out_idx + N_TOK;              // 1

  float* esq = (float*)d_ws;       // K floats
  float* bl  = esq + K;            // NBLK floats

  esq_kernel<<<1, K, 0, stream>>>(emb, esq);
  vq_main<<<NBLK, BLK, 0, stream>>>(z_e, emb, esq, out_zq, out_idx, bl);
  loss_finalize<<<1, 256, 0, stream>>>(bl, out_loss);
}